// Round 2
// baseline (77.329 us; speedup 1.0000x reference)
//
#include <hip/hip_runtime.h>
#include <cstdint>

// OctantQuery: pcs [B,3,N] f32 -> out [B,N,9,K] int32.
// One wave (64 lanes) per center point; 8 waves (512 threads) per block.
// All 8 waves of a block share the same batch b (8 | 2048), so the block
// stages the whole batch's coords (3 x 8KB) into LDS once, and the main
// scan loop reads candidates from LDS only (no global loads -> no L2
// latency on the critical path). A 1-chunk register prefetch overlaps the
// ds_read latency with the ballot/octant processing of the current chunk.
// Self-exclusion (j != i) is a wave-uniform SALU mask clear on the single
// chunk containing i, not a per-lane VALU compare.

#define NPTS   2048
#define KSAMP  32
#define RAD2   0.16f
#define WPB    8            // waves per block
#define BLOCK  (WPB * 64)   // 512 threads; 24KB LDS -> 4 blocks/CU = 32 waves/CU

__device__ __forceinline__ unsigned rank_below(unsigned long long mask) {
    // number of set bits in `mask` at lane positions strictly below mine
    return __builtin_amdgcn_mbcnt_hi((unsigned)(mask >> 32),
           __builtin_amdgcn_mbcnt_lo((unsigned)(mask & 0xffffffffu), 0u));
}

__global__ __launch_bounds__(BLOCK) void octant_query_kernel(
    const float* __restrict__ pcs, int* __restrict__ out, int nwaves) {
#pragma clang fp contract(off)
    __shared__ float sx[NPTS];
    __shared__ float sy[NPTS];
    __shared__ float sz[NPTS];

    const int tid  = (int)threadIdx.x;
    const int wid  = tid >> 6;
    const int lane = tid & 63;
    const int wave = (int)blockIdx.x * WPB + wid;
    const int b    = (wave - wid) >> 11;     // block-uniform batch (8 | 2048)

    const float* __restrict__ px = pcs + (size_t)b * 3 * NPTS;
    const float* __restrict__ py = px + NPTS;
    const float* __restrict__ pz = py + NPTS;

    // One-time stage: 3 x 8KB -> LDS, float4-coalesced (2048 floats = 512 float4).
    {
        const float4 vx = ((const float4*)px)[tid];
        const float4 vy = ((const float4*)py)[tid];
        const float4 vz = ((const float4*)pz)[tid];
        ((float4*)sx)[tid] = vx;
        ((float4*)sy)[tid] = vy;
        ((float4*)sz)[tid] = vz;
    }
    __syncthreads();

    if (wave >= nwaves) return;   // grid is exact; placed after the barrier

    const int i = wave & (NPTS - 1);
    const float cx = sx[i];
    const float cy = sy[i];
    const float cz = sz[i];

    int* __restrict__ obase = out + (size_t)(b * NPTS + i) * 9 * KSAMP;
    const int ichunk = i >> 6;                             // chunk holding i
    const unsigned long long notself = ~(1ULL << (i & 63));

    int cnt0 = 0, cnt1 = 0, cnt2 = 0, cnt3 = 0;
    int cnt4 = 0, cnt5 = 0, cnt6 = 0, cnt7 = 0;

    // register prefetch of chunk 0
    float jx = sx[lane];
    float jy = sy[lane];
    float jz = sz[lane];

    for (int c = 0; c < NPTS; c += 64) {
        const float dx = jx - cx;
        const float dy = jy - cy;
        const float dz = jz - cz;

        // prefetch next chunk (wraps to 0 on last iter -- harmless, branchless)
        const int cn = (c + 64) & (NPTS - 1);
        jx = sx[cn + lane];
        jy = sy[cn + lane];
        jz = sz[cn + lane];

        // match numpy rounding: no fp contraction (pragma above), left-assoc
        float d2 = dx * dx;
        d2 = d2 + dy * dy;
        d2 = d2 + dz * dz;

        unsigned long long mw = __ballot(d2 < RAD2);
        if ((c >> 6) == ichunk) mw &= notself;   // wave-uniform self-exclusion
        if (mw == 0ULL) continue;                // wave-uniform skip (~70%)

        const unsigned long long mx = __ballot(dx > 0.f);
        const unsigned long long my = __ballot(dy > 0.f);
        const unsigned long long mz = __ballot(dz > 0.f);
        const int j = c + lane;

#define DO_OCT(o, cnt)                                                      \
        {                                                                   \
            unsigned long long m = mw;                                      \
            m &= ((o) & 1) ? mx : ~mx;                                      \
            m &= ((o) & 2) ? my : ~my;                                      \
            m &= ((o) & 4) ? mz : ~mz;                                      \
            if (m) {                              /* uniform skip */        \
                const bool mine = (m >> lane) & 1ULL;                       \
                if (mine) {                                                 \
                    const int r = cnt + (int)rank_below(m);                 \
                    if (r < KSAMP) obase[(o) * KSAMP + r] = j;              \
                }                                                           \
                cnt += (int)__popcll(m);                                    \
            }                                                               \
        }
        DO_OCT(0, cnt0) DO_OCT(1, cnt1) DO_OCT(2, cnt2) DO_OCT(3, cnt3)
        DO_OCT(4, cnt4) DO_OCT(5, cnt5) DO_OCT(6, cnt6) DO_OCT(7, cnt7)
#undef DO_OCT
    }

    // pad remaining slots with center index i (each slot written exactly once)
#define FILL(o, cnt)                                                        \
        {                                                                   \
            const int s = cnt + lane;                                       \
            if (s < KSAMP) obase[(o) * KSAMP + s] = i;                      \
        }
    FILL(0, cnt0) FILL(1, cnt1) FILL(2, cnt2) FILL(3, cnt3)
    FILL(4, cnt4) FILL(5, cnt5) FILL(6, cnt6) FILL(7, cnt7)
#undef FILL
    if (lane < KSAMP) obase[8 * KSAMP + lane] = i;
}

extern "C" void kernel_launch(void* const* d_in, const int* in_sizes, int n_in,
                              void* d_out, int out_size, void* d_ws, size_t ws_size,
                              hipStream_t stream) {
    const float* pcs = (const float*)d_in[0];
    int* out = (int*)d_out;
    const int B = in_sizes[0] / (3 * NPTS);   // 4
    const int nwaves = B * NPTS;              // one wave per center point
    const int grid = nwaves / WPB;            // WPB | 2048 -> exact
    octant_query_kernel<<<grid, BLOCK, 0, stream>>>(pcs, out, nwaves);
}

// Round 4
// 75.711 us; speedup vs baseline: 1.0214x; 1.0214x over previous
//
#include <hip/hip_runtime.h>
#include <cstdint>

// OctantQuery: pcs [B,3,N] f32 -> out [B,N,9,K] int32.
// One wave (64 lanes) per center point. Lanes scan 64 candidate j's per
// chunk. The batch's coords (24 KB) are L1-resident, so candidate loads are
// L1 hits; the key structure is batching 4 chunks' loads (12 global loads)
// per group so the L1 latency is exposed once per group (8x/wave) instead of
// once per chunk (32x/wave). Ballot/octant processing is wave-uniform and
// skipped for empty chunks (~70%). Self-exclusion (j != i) is a wave-uniform
// SALU mask clear on the single chunk containing i. Octant masks are built
// via a shared-subexpression tree (14 s_and_b64 instead of 24).

#define NPTS   2048
#define KSAMP  32
#define RAD2   0.16f

__device__ __forceinline__ unsigned rank_below(unsigned long long mask) {
    // number of set bits in `mask` at lane positions strictly below mine
    return __builtin_amdgcn_mbcnt_hi((unsigned)(mask >> 32),
           __builtin_amdgcn_mbcnt_lo((unsigned)(mask & 0xffffffffu), 0u));
}

__global__ __launch_bounds__(256) void octant_query_kernel(
    const float* __restrict__ pcs, int* __restrict__ out, int nwaves) {
#pragma clang fp contract(off)
    const int wave = (int)((blockIdx.x * blockDim.x + threadIdx.x) >> 6);
    const int lane = (int)(threadIdx.x & 63);
    if (wave >= nwaves) return;
    const int b = wave >> 11;        // N = 2048
    const int i = wave & (NPTS - 1);

    const float* __restrict__ px = pcs + (size_t)b * 3 * NPTS;
    const float* __restrict__ py = px + NPTS;
    const float* __restrict__ pz = py + NPTS;

    const float cx = px[i];
    const float cy = py[i];
    const float cz = pz[i];

    int* __restrict__ obase = out + (size_t)(b * NPTS + i) * 9 * KSAMP;
    const int ichunk = i >> 6;                             // chunk holding i
    const unsigned long long notself = ~(1ULL << (i & 63));

    int cnt0 = 0, cnt1 = 0, cnt2 = 0, cnt3 = 0;
    int cnt4 = 0, cnt5 = 0, cnt6 = 0, cnt7 = 0;

#define DO_OCT(o, mexpr, cnt)                                               \
        {                                                                   \
            const unsigned long long m = (mexpr);                           \
            if (m) {                              /* uniform skip */        \
                if ((m >> lane) & 1ULL) {                                   \
                    const int r = cnt + (int)rank_below(m);                 \
                    if (r < KSAMP) obase[(o) * KSAMP + r] = j;              \
                }                                                           \
                cnt += (int)__popcll(m);                                    \
            }                                                               \
        }

#define PROC(q, xx, yy, zz)                                                 \
        {                                                                   \
            const int c = g + (q) * 64;                                     \
            const float dx = (xx) - cx;                                     \
            const float dy = (yy) - cy;                                     \
            const float dz = (zz) - cz;                                     \
            /* match numpy rounding: contract off, left-assoc */            \
            float d2 = dx * dx;                                             \
            d2 = d2 + dy * dy;                                              \
            d2 = d2 + dz * dz;                                              \
            unsigned long long mw = __ballot(d2 < RAD2);                    \
            if ((c >> 6) == ichunk) mw &= notself;  /* uniform self-excl */ \
            if (mw != 0ULL) {                       /* uniform skip ~70% */ \
                const unsigned long long mx = __ballot(dx > 0.f);           \
                const unsigned long long my = __ballot(dy > 0.f);           \
                const unsigned long long mz = __ballot(dz > 0.f);           \
                const int j = c + lane;                                     \
                const unsigned long long a0 = mw & ~mx, a1 = mw & mx;       \
                const unsigned long long b0 = a0 & ~my, b1 = a1 & ~my;      \
                const unsigned long long b2 = a0 &  my, b3 = a1 &  my;      \
                DO_OCT(0, b0 & ~mz, cnt0)                                   \
                DO_OCT(1, b1 & ~mz, cnt1)                                   \
                DO_OCT(2, b2 & ~mz, cnt2)                                   \
                DO_OCT(3, b3 & ~mz, cnt3)                                   \
                DO_OCT(4, b0 &  mz, cnt4)                                   \
                DO_OCT(5, b1 &  mz, cnt5)                                   \
                DO_OCT(6, b2 &  mz, cnt6)                                   \
                DO_OCT(7, b3 &  mz, cnt7)                                   \
            }                                                               \
        }

    for (int g = 0; g < NPTS; g += 256) {
        // 12 independent loads issued back-to-back: one L1-latency exposure
        // per 4 chunks instead of per chunk.
        const float x0 = px[g +   0 + lane];
        const float y0 = py[g +   0 + lane];
        const float z0 = pz[g +   0 + lane];
        const float x1 = px[g +  64 + lane];
        const float y1 = py[g +  64 + lane];
        const float z1 = pz[g +  64 + lane];
        const float x2 = px[g + 128 + lane];
        const float y2 = py[g + 128 + lane];
        const float z2 = pz[g + 128 + lane];
        const float x3 = px[g + 192 + lane];
        const float y3 = py[g + 192 + lane];
        const float z3 = pz[g + 192 + lane];

        PROC(0, x0, y0, z0)
        PROC(1, x1, y1, z1)
        PROC(2, x2, y2, z2)
        PROC(3, x3, y3, z3)
    }
#undef PROC
#undef DO_OCT

    // pad remaining slots with center index i (each slot written exactly once)
#define FILL(o, cnt)                                                        \
        {                                                                   \
            const int s = cnt + lane;                                       \
            if (s < KSAMP) obase[(o) * KSAMP + s] = i;                      \
        }
    FILL(0, cnt0) FILL(1, cnt1) FILL(2, cnt2) FILL(3, cnt3)
    FILL(4, cnt4) FILL(5, cnt5) FILL(6, cnt6) FILL(7, cnt7)
#undef FILL
    if (lane < KSAMP) obase[8 * KSAMP + lane] = i;
}

extern "C" void kernel_launch(void* const* d_in, const int* in_sizes, int n_in,
                              void* d_out, int out_size, void* d_ws, size_t ws_size,
                              hipStream_t stream) {
    const float* pcs = (const float*)d_in[0];
    int* out = (int*)d_out;
    const int B = in_sizes[0] / (3 * NPTS);   // 4
    const int nwaves = B * NPTS;              // one wave per center
    const int block = 256;                    // 4 waves/block
    const int grid = (nwaves * 64 + block - 1) / block;
    octant_query_kernel<<<grid, block, 0, stream>>>(pcs, out, nwaves);
}